// Round 1
// baseline (387.682 us; speedup 1.0000x reference)
//
#include <hip/hip_runtime.h>

#define BB 16
#define CC 64
#define NN 4096      // H*W = 64*64
#define MM 1024      // pooled spatial (32*32)

// workspace layout (floats):
// theta [B][N][8]  : offset 0        (524288)
// phi   [B][M][8]  : offset 524288   (131072)
// g     [B][M][32] : offset 655360   (524288)
// o     [B][N][32] : offset 1179648  (2097152)
// total 3276800 floats = 13.1 MB

// ---------------------------------------------------------------------------
// Kernel 1: theta (full res) + phi/g (conv then 2x2 maxpool)
// grid (32, 16): blockIdx.x = image-row-pair tile (2 rows = 128 px = 1 pooled row),
// blockIdx.y = batch. 256 threads.
// ---------------------------------------------------------------------------
__global__ __launch_bounds__(256) void prep_kernel(
    const float* __restrict__ x, const float* __restrict__ w_theta,
    const float* __restrict__ w_phi, const float* __restrict__ w_g,
    float* __restrict__ theta, float* __restrict__ phi, float* __restrict__ g)
{
    __shared__ float xs[64 * 128];   // [c][local_px], 2 image rows
    __shared__ float wth[8 * 64];
    __shared__ float wpg[40 * 64];   // rows 0..7 = w_phi, 8..39 = w_g

    const int t = threadIdx.x;
    const int b = blockIdx.y;
    const int tile = blockIdx.x;         // pooled row index (0..31)
    const int nbase = tile * 128;        // first pixel of the 2-row tile

    for (int i = t; i < 8 * 64; i += 256)  wth[i] = w_theta[i];
    for (int i = t; i < 8 * 64; i += 256)  wpg[i] = w_phi[i];
    for (int i = t; i < 32 * 64; i += 256) wpg[512 + i] = w_g[i];

    const float* xb = x + (size_t)b * CC * NN;
    for (int i = t; i < 64 * 128; i += 256) {
        int c = i >> 7, p = i & 127;
        xs[c * 128 + p] = xb[c * NN + nbase + p];
    }
    __syncthreads();

    // ---- theta: thread -> (pixel p = t&127, output-half oh = t>>7) ----
    {
        const int p = t & 127, oh = t >> 7;
        float acc[4] = {0.f, 0.f, 0.f, 0.f};
        for (int c = 0; c < 64; ++c) {
            float xv = xs[c * 128 + p];
            #pragma unroll
            for (int k = 0; k < 4; ++k) acc[k] += wth[(oh * 4 + k) * 64 + c] * xv;
        }
        float* dst = theta + ((size_t)b * NN + nbase + p) * 8 + oh * 4;
        #pragma unroll
        for (int k = 0; k < 4; ++k) dst[k] = acc[k];
    }

    // ---- pooled phi+g: thread -> (pooled col ml = t&31, part = t>>5, 5 outputs) ----
    {
        const int ml = t & 31, part = t >> 5;
        const int p0 = ml * 2;
        float acc[5];
        #pragma unroll
        for (int k = 0; k < 5; ++k) acc[k] = -1e30f;
        #pragma unroll
        for (int px = 0; px < 4; ++px) {
            const int pl = p0 + (px & 1) + (px >> 1) * 64;  // W=64 row stride
            float s[5] = {0.f, 0.f, 0.f, 0.f, 0.f};
            for (int c = 0; c < 64; ++c) {
                float xv = xs[c * 128 + pl];
                #pragma unroll
                for (int k = 0; k < 5; ++k) s[k] += wpg[(part * 5 + k) * 64 + c] * xv;
            }
            #pragma unroll
            for (int k = 0; k < 5; ++k) acc[k] = fmaxf(acc[k], s[k]);
        }
        const int m = tile * 32 + ml;    // pooled index, h2 = tile, w2 = ml
        #pragma unroll
        for (int k = 0; k < 5; ++k) {
            const int o = part * 5 + k;
            if (o < 8) phi[((size_t)b * MM + m) * 8 + o] = acc[k];
            else       g[((size_t)b * MM + m) * 32 + (o - 8)] = acc[k];
        }
    }
}

// ---------------------------------------------------------------------------
// Kernel 2: flash attention. grid (64, 16), 256 threads.
// lane = query (64 queries/block), wave = key-quarter (kp = t>>6).
// All key-indexed LDS reads are wave-uniform -> broadcast, conflict-free.
// ---------------------------------------------------------------------------
__global__ __launch_bounds__(256) void attn_kernel(
    const float* __restrict__ theta, const float* __restrict__ phi,
    const float* __restrict__ g, float* __restrict__ o_ws)
{
    __shared__ float smem[16384];        // 64 KB
    float* phs = smem;                   // [1024][8]  phi, whole batch
    float* gs  = smem + 8192;            // [256][32]  g chunk

    const int t  = threadIdx.x;
    const int b  = blockIdx.y;
    const int qt = blockIdx.x;
    const int q  = t & 63, kp = t >> 6;
    const int qg = qt * 64 + q;

    const float* phib = phi + (size_t)b * MM * 8;
    for (int i = t; i < 8192; i += 256) phs[i] = phib[i];

    float th[8];
    const float* thp = theta + ((size_t)b * NN + qg) * 8;
    #pragma unroll
    for (int k = 0; k < 8; ++k) th[k] = thp[k];

    float m_i = -1e30f, l_i = 0.f;
    float oacc[32];
    #pragma unroll
    for (int d = 0; d < 32; ++d) oacc[d] = 0.f;

    const float* gb = g + (size_t)b * MM * 32;
    for (int chunk = 0; chunk < 4; ++chunk) {
        __syncthreads();   // protect gs from previous iteration's readers
        for (int i = t; i < 8192; i += 256) gs[i] = gb[chunk * 8192 + i];
        __syncthreads();

        const int mb = chunk * 256 + kp * 64;   // global key base (phs index)

        // pass 1: chunk max
        float cm = m_i;
        for (int j = 0; j < 64; ++j) {
            const float* pm = phs + (mb + j) * 8;
            float s = th[0]*pm[0] + th[1]*pm[1] + th[2]*pm[2] + th[3]*pm[3]
                    + th[4]*pm[4] + th[5]*pm[5] + th[6]*pm[6] + th[7]*pm[7];
            cm = fmaxf(cm, s);
        }
        // rescale running state
        const float alpha = __expf(m_i - cm);
        l_i *= alpha;
        #pragma unroll
        for (int d = 0; d < 32; ++d) oacc[d] *= alpha;
        m_i = cm;

        // pass 2: accumulate
        for (int j = 0; j < 64; ++j) {
            const float* pm = phs + (mb + j) * 8;
            float s = th[0]*pm[0] + th[1]*pm[1] + th[2]*pm[2] + th[3]*pm[3]
                    + th[4]*pm[4] + th[5]*pm[5] + th[6]*pm[6] + th[7]*pm[7];
            const float p = __expf(s - m_i);
            l_i += p;
            const float* gv = gs + (kp * 64 + j) * 32;
            #pragma unroll
            for (int d = 0; d < 32; ++d) oacc[d] += p * gv[d];
        }
    }

    // ---- merge the 4 key-quarter partials (overlay on smem, all prior data dead) ----
    __syncthreads();
    float* mbuf = smem;              // [4][64]
    float* lbuf = smem + 256;        // [4][64]
    float* obuf = smem + 512;        // [4][32][64], q-minor -> conflict-free
    mbuf[kp * 64 + q] = m_i;
    lbuf[kp * 64 + q] = l_i;
    #pragma unroll
    for (int d = 0; d < 32; ++d) obuf[kp * 2048 + d * 64 + q] = oacc[d];
    __syncthreads();

    if (t < 64) {
        const float M0 = mbuf[q], M1 = mbuf[64 + q], M2 = mbuf[128 + q], M3 = mbuf[192 + q];
        const float Mx = fmaxf(fmaxf(M0, M1), fmaxf(M2, M3));
        const float a0 = __expf(M0 - Mx), a1 = __expf(M1 - Mx);
        const float a2 = __expf(M2 - Mx), a3 = __expf(M3 - Mx);
        const float L = lbuf[q] * a0 + lbuf[64 + q] * a1 + lbuf[128 + q] * a2 + lbuf[192 + q] * a3;
        const float inv = 1.f / L;
        float* dst = o_ws + ((size_t)b * NN + qg) * 32;
        #pragma unroll
        for (int d = 0; d < 32; ++d) {
            float v = obuf[d * 64 + q] * a0 + obuf[2048 + d * 64 + q] * a1
                    + obuf[4096 + d * 64 + q] * a2 + obuf[6144 + d * 64 + q] * a3;
            dst[d] = v * inv;
        }
    }
}

// ---------------------------------------------------------------------------
// Kernel 3: out = gamma * (w_o @ o) + x. grid (32, 16), 256 threads.
// blockIdx.x < 16 -> channels 0..31, >=16 -> channels 32..63 (half uniform/block).
// ---------------------------------------------------------------------------
__global__ __launch_bounds__(256) void out_kernel(
    const float* __restrict__ o_ws, const float* __restrict__ w_o,
    const float* __restrict__ x, const float* __restrict__ gamma_p,
    float* __restrict__ out)
{
    __shared__ float wos[64 * 32];
    const int t = threadIdx.x;
    for (int i = t; i < 2048; i += 256) wos[i] = w_o[i];
    __syncthreads();

    const int b = blockIdx.y;
    const int xid = blockIdx.x * 256 + t;   // 0..8191
    const int half = xid >> 12;             // uniform per block
    const int n = xid & 4095;
    const float gamma = *gamma_p;

    float ov[32];
    const float* op = o_ws + ((size_t)b * NN + n) * 32;
    #pragma unroll
    for (int d = 0; d < 32; ++d) ov[d] = op[d];

    const float* xb = x + (size_t)b * CC * NN;
    float* ob = out + (size_t)b * CC * NN;
    for (int ci = 0; ci < 32; ++ci) {
        const int c = half * 32 + ci;
        const float* wr = wos + c * 32;
        float acc = 0.f;
        #pragma unroll
        for (int d = 0; d < 32; ++d) acc += wr[d] * ov[d];
        ob[c * NN + n] = gamma * acc + xb[c * NN + n];
    }
}

// ---------------------------------------------------------------------------
extern "C" void kernel_launch(void* const* d_in, const int* in_sizes, int n_in,
                              void* d_out, int out_size, void* d_ws, size_t ws_size,
                              hipStream_t stream) {
    const float* x       = (const float*)d_in[0];
    const float* w_theta = (const float*)d_in[1];
    const float* w_phi   = (const float*)d_in[2];
    const float* w_g     = (const float*)d_in[3];
    const float* w_o     = (const float*)d_in[4];
    const float* gamma   = (const float*)d_in[5];

    float* ws    = (float*)d_ws;
    float* theta = ws;
    float* phi   = ws + 524288;
    float* g     = ws + 655360;
    float* o     = ws + 1179648;
    float* out   = (float*)d_out;

    prep_kernel<<<dim3(32, 16), 256, 0, stream>>>(x, w_theta, w_phi, w_g, theta, phi, g);
    attn_kernel<<<dim3(64, 16), 256, 0, stream>>>(theta, phi, g, o);
    out_kernel<<<dim3(32, 16), 256, 0, stream>>>(o, w_o, x, gamma, out);
}

// Round 2
// 332.896 us; speedup vs baseline: 1.1646x; 1.1646x over previous
//
#include <hip/hip_runtime.h>

#define BB 16
#define CC 64
#define NN 4096      // H*W = 64*64
#define MM 1024      // pooled spatial (32*32)

// workspace layout (floats):
// theta [B][N][8]  : offset 0        (524288)
// phi   [B][M][8]  : offset 524288   (131072)
// g     [B][M][32] : offset 655360   (524288)
// o     [B][N][32] : offset 1179648  (2097152)

// ---------------------------------------------------------------------------
// Kernel 1: all three 1x1 convs + 2x2 maxpool for phi/g.
// grid (16, 16): blockIdx.x = 4-image-row group (256 px), blockIdx.y = batch.
// Thread per pixel. 48 conv outputs/thread: k 0..7 theta, 8..15 phi, 16..47 g.
// Weights transposed in LDS -> wave-uniform float4 broadcasts (conflict-free).
// x prefetched to xr[64] registers (64 coalesced loads, latency overlapped).
// Pooling: horizontal via __shfl_xor(1) (same wave), vertical via 20KB LDS.
// ---------------------------------------------------------------------------
__global__ __launch_bounds__(256) void prep_kernel(
    const float* __restrict__ x, const float* __restrict__ w_theta,
    const float* __restrict__ w_phi, const float* __restrict__ w_g,
    float* __restrict__ theta, float* __restrict__ phi, float* __restrict__ g)
{
    __shared__ float wT[64 * 48];    // [c][k] transposed weights, 12 KB
    __shared__ float pool[40 * 128]; // [k][rp(4)][pooled_col(32)], 20 KB

    const int t = threadIdx.x;
    const int b = blockIdx.y;

    for (int i = t; i < 64 * 8; i += 256)  { int o = i >> 6, c = i & 63; wT[c * 48 + o] = w_theta[i]; }
    for (int i = t; i < 64 * 8; i += 256)  { int o = i >> 6, c = i & 63; wT[c * 48 + 8 + o] = w_phi[i]; }
    for (int i = t; i < 64 * 32; i += 256) { int o = i >> 6, c = i & 63; wT[c * 48 + 16 + o] = w_g[i]; }
    __syncthreads();

    const int p = blockIdx.x * 256 + t;            // pixel in image
    const float* xb = x + (size_t)b * CC * NN;

    // prefetch all 64 channel values for this pixel (coalesced across lanes)
    float xr[64];
    #pragma unroll
    for (int c = 0; c < 64; ++c) xr[c] = xb[c * NN + p];

    float4 acc[12];
    #pragma unroll
    for (int k = 0; k < 12; ++k) acc[k] = make_float4(0.f, 0.f, 0.f, 0.f);

    #pragma unroll
    for (int c = 0; c < 64; ++c) {
        const float xv = xr[c];
        const float4* w4 = (const float4*)&wT[c * 48];
        #pragma unroll
        for (int k = 0; k < 12; ++k) {
            float4 w = w4[k];
            acc[k].x += w.x * xv; acc[k].y += w.y * xv;
            acc[k].z += w.z * xv; acc[k].w += w.w * xv;
        }
    }

    // theta out (contiguous 2KB per wave)
    float4* thdst = (float4*)(theta + ((size_t)b * NN + p) * 8);
    thdst[0] = acc[0]; thdst[1] = acc[1];

    // horizontal pool: cols (2i,2i+1) are lanes t, t^1 (same wave)
    const int col = t & 63, rp = t >> 6;
    float hm[40];
    #pragma unroll
    for (int k = 0; k < 10; ++k) {
        float4 a = acc[2 + k];
        hm[4 * k + 0] = a.x; hm[4 * k + 1] = a.y; hm[4 * k + 2] = a.z; hm[4 * k + 3] = a.w;
    }
    #pragma unroll
    for (int k = 0; k < 40; ++k) {
        float o = __shfl_xor(hm[k], 1, 64);
        hm[k] = fmaxf(hm[k], o);
    }
    if ((col & 1) == 0) {
        const int pc = col >> 1;
        #pragma unroll
        for (int k = 0; k < 40; ++k) pool[k * 128 + rp * 32 + pc] = hm[k];
    }
    __syncthreads();

    // vertical pool: rows (2pr, 2pr+1); 2560 outputs, 10 per thread
    const int mrow0 = blockIdx.x * 2;
    for (int i = t; i < 2560; i += 256) {
        const int k = i >> 6, rem = i & 63, pr = rem >> 5, pcol = rem & 31;
        const float v = fmaxf(pool[k * 128 + (2 * pr) * 32 + pcol],
                              pool[k * 128 + (2 * pr + 1) * 32 + pcol]);
        const int m = (mrow0 + pr) * 32 + pcol;
        if (k < 8) phi[((size_t)b * MM + m) * 8 + k] = v;
        else       g[((size_t)b * MM + m) * 32 + (k - 8)] = v;
    }
}

// ---------------------------------------------------------------------------
// Kernel 2: flash attention. grid (64, 16), 256 threads.
// lane = query (64 q/block), wave kp = key-quarter (64 keys/chunk each).
// Scores cached in s[64] registers (single QK pass). All key-indexed LDS
// reads are wave-uniform float4 -> broadcast ds_read_b128, conflict-free.
// LDS 40KB -> 4 blocks/CU; grid 1024 = full residency.
// ---------------------------------------------------------------------------
__global__ __launch_bounds__(256) void attn_kernel(
    const float* __restrict__ theta, const float* __restrict__ phi,
    const float* __restrict__ g, float* __restrict__ o_ws)
{
    __shared__ float smem[10240];            // 40 KB
    float4* phs = (float4*)smem;             // [256 keys][2] float4  (8 KB)
    float4* gs  = (float4*)(smem + 2048);    // [256 keys][8] float4  (32 KB)

    const int t  = threadIdx.x;
    const int b  = blockIdx.y;
    const int qt = blockIdx.x;
    const int q  = t & 63, kp = t >> 6;
    const int qg = qt * 64 + q;

    float4 th0, th1;
    {
        const float4* thp = (const float4*)(theta + ((size_t)b * NN + qg) * 8);
        th0 = thp[0]; th1 = thp[1];
    }

    float m_i = -1e30f, l_i = 0.f;
    float4 oa[8];
    #pragma unroll
    for (int d = 0; d < 8; ++d) oa[d] = make_float4(0.f, 0.f, 0.f, 0.f);

    const float4* phib = (const float4*)phi + (size_t)b * (MM * 8 / 4);
    const float4* gb   = (const float4*)g   + (size_t)b * (MM * 32 / 4);

    for (int chunk = 0; chunk < 4; ++chunk) {
        __syncthreads();
        for (int i = t; i < 512; i += 256)  phs[i] = phib[chunk * 512 + i];
        for (int i = t; i < 2048; i += 256) gs[i]  = gb[chunk * 2048 + i];
        __syncthreads();

        const int kb = kp * 64;

        float s[64];
        float cm = m_i;
        #pragma unroll
        for (int j = 0; j < 64; ++j) {
            const float4 p0 = phs[(kb + j) * 2];
            const float4 p1 = phs[(kb + j) * 2 + 1];
            const float sv = th0.x * p0.x + th0.y * p0.y + th0.z * p0.z + th0.w * p0.w
                           + th1.x * p1.x + th1.y * p1.y + th1.z * p1.z + th1.w * p1.w;
            s[j] = sv;
            cm = fmaxf(cm, sv);
        }

        const float alpha = __expf(m_i - cm);
        l_i *= alpha;
        #pragma unroll
        for (int d = 0; d < 8; ++d) {
            oa[d].x *= alpha; oa[d].y *= alpha; oa[d].z *= alpha; oa[d].w *= alpha;
        }
        m_i = cm;

        #pragma unroll
        for (int j = 0; j < 64; ++j) {
            const float pw = __expf(s[j] - cm);
            l_i += pw;
            const float4* gv = &gs[(kb + j) * 8];
            #pragma unroll
            for (int d = 0; d < 8; ++d) {
                const float4 gg = gv[d];
                oa[d].x += pw * gg.x; oa[d].y += pw * gg.y;
                oa[d].z += pw * gg.z; oa[d].w += pw * gg.w;
            }
        }
    }

    // merge the 4 key-quarter partials (overlay smem; all prior data dead)
    __syncthreads();
    float* mbuf = smem;              // [4][64]
    float* lbuf = smem + 256;        // [4][64]
    float* obuf = smem + 512;        // [4][32][64] q-minor -> conflict-free
    mbuf[kp * 64 + q] = m_i;
    lbuf[kp * 64 + q] = l_i;
    #pragma unroll
    for (int d = 0; d < 8; ++d) {
        obuf[kp * 2048 + (4 * d + 0) * 64 + q] = oa[d].x;
        obuf[kp * 2048 + (4 * d + 1) * 64 + q] = oa[d].y;
        obuf[kp * 2048 + (4 * d + 2) * 64 + q] = oa[d].z;
        obuf[kp * 2048 + (4 * d + 3) * 64 + q] = oa[d].w;
    }
    __syncthreads();

    if (t < 64) {
        const float M0 = mbuf[q], M1 = mbuf[64 + q], M2 = mbuf[128 + q], M3 = mbuf[192 + q];
        const float Mx = fmaxf(fmaxf(M0, M1), fmaxf(M2, M3));
        const float a0 = __expf(M0 - Mx), a1 = __expf(M1 - Mx);
        const float a2 = __expf(M2 - Mx), a3 = __expf(M3 - Mx);
        const float L = lbuf[q] * a0 + lbuf[64 + q] * a1 + lbuf[128 + q] * a2 + lbuf[192 + q] * a3;
        const float inv = 1.f / L;
        float* dst = o_ws + ((size_t)b * NN + qg) * 32;
        #pragma unroll
        for (int d = 0; d < 32; ++d) {
            float v = obuf[d * 64 + q] * a0 + obuf[2048 + d * 64 + q] * a1
                    + obuf[4096 + d * 64 + q] * a2 + obuf[6144 + d * 64 + q] * a3;
            dst[d] = v * inv;
        }
    }
}

// ---------------------------------------------------------------------------
// Kernel 3: out = gamma * (w_o @ o) + x. grid (32, 16), 256 threads.
// ---------------------------------------------------------------------------
__global__ __launch_bounds__(256) void out_kernel(
    const float* __restrict__ o_ws, const float* __restrict__ w_o,
    const float* __restrict__ x, const float* __restrict__ gamma_p,
    float* __restrict__ out)
{
    __shared__ float wos[64 * 32];
    const int t = threadIdx.x;
    for (int i = t; i < 2048; i += 256) wos[i] = w_o[i];
    __syncthreads();

    const int b = blockIdx.y;
    const int xid = blockIdx.x * 256 + t;   // 0..8191
    const int half = xid >> 12;             // uniform per block
    const int n = xid & 4095;
    const float gamma = *gamma_p;

    float4 ov[8];
    const float4* op = (const float4*)(o_ws + ((size_t)b * NN + n) * 32);
    #pragma unroll
    for (int d = 0; d < 8; ++d) ov[d] = op[d];

    const float* xb = x + (size_t)b * CC * NN;
    float* ob = out + (size_t)b * CC * NN;
    for (int ci = 0; ci < 32; ++ci) {
        const int c = half * 32 + ci;
        const float4* wr = (const float4*)(wos + c * 32);
        float acc = 0.f;
        #pragma unroll
        for (int d = 0; d < 8; ++d) {
            const float4 w = wr[d];
            acc += w.x * ov[d].x + w.y * ov[d].y + w.z * ov[d].z + w.w * ov[d].w;
        }
        ob[c * NN + n] = gamma * acc + xb[c * NN + n];
    }
}

// ---------------------------------------------------------------------------
extern "C" void kernel_launch(void* const* d_in, const int* in_sizes, int n_in,
                              void* d_out, int out_size, void* d_ws, size_t ws_size,
                              hipStream_t stream) {
    const float* x       = (const float*)d_in[0];
    const float* w_theta = (const float*)d_in[1];
    const float* w_phi   = (const float*)d_in[2];
    const float* w_g     = (const float*)d_in[3];
    const float* w_o     = (const float*)d_in[4];
    const float* gamma   = (const float*)d_in[5];

    float* ws    = (float*)d_ws;
    float* theta = ws;
    float* phi   = ws + 524288;
    float* g     = ws + 655360;
    float* o     = ws + 1179648;
    float* out   = (float*)d_out;

    prep_kernel<<<dim3(16, 16), 256, 0, stream>>>(x, w_theta, w_phi, w_g, theta, phi, g);
    attn_kernel<<<dim3(64, 16), 256, 0, stream>>>(theta, phi, g, o);
    out_kernel<<<dim3(32, 16), 256, 0, stream>>>(o, w_o, x, gamma, out);
}

// Round 3
// 137.068 us; speedup vs baseline: 2.8284x; 2.4287x over previous
//
#include <hip/hip_runtime.h>
#include <hip/hip_bf16.h>

#define BB 16
#define CC 64
#define NN 4096      // H*W
#define MM 1024      // pooled spatial

typedef unsigned short u16;
typedef __attribute__((ext_vector_type(8))) short bf16x8;
typedef __attribute__((ext_vector_type(4))) float f32x4;

__device__ inline u16 f2bf(float f) {
    union { float f; unsigned u; } v; v.f = f;
    return (u16)((v.u + 0x7FFFu + ((v.u >> 16) & 1u)) >> 16);
}
__device__ inline bf16x8 ld_bf16x8(const u16* p) {
    union { uint4 u; bf16x8 b; } c; c.u = *(const uint4*)p; return c.b;
}

// workspace (floats):
// o_ws    [B][N][32] fp32 : offset 0        (2097152 floats, 8 MB)
// theta_b [B][N][8]  bf16 : ws+2097152      (524288 u16, 1 MB)
// phi_b   [B][M][8]  bf16 : +524288 u16     (131072 u16)
// gT_b    [B][32][M] bf16 : +131072 u16     (524288 u16)

// ---------------------------------------------------------------------------
// Kernel 1: 1x1 convs + 2x2 maxpool; emits bf16 theta/phi/gT.
// grid (16,16): blockIdx.x = 4-image-row group (256 px), blockIdx.y = batch.
// ---------------------------------------------------------------------------
__global__ __launch_bounds__(256) void prep_kernel(
    const float* __restrict__ x, const float* __restrict__ w_theta,
    const float* __restrict__ w_phi, const float* __restrict__ w_g,
    u16* __restrict__ theta_b, u16* __restrict__ phi_b, u16* __restrict__ gT_b)
{
    __shared__ float wT[64 * 48];    // [c][k] transposed weights
    __shared__ float pool[40 * 128]; // [k][rp(4)][pooled_col(32)]

    const int t = threadIdx.x;
    const int b = blockIdx.y;

    for (int i = t; i < 64 * 8; i += 256)  { int o = i >> 6, c = i & 63; wT[c * 48 + o] = w_theta[i]; }
    for (int i = t; i < 64 * 8; i += 256)  { int o = i >> 6, c = i & 63; wT[c * 48 + 8 + o] = w_phi[i]; }
    for (int i = t; i < 64 * 32; i += 256) { int o = i >> 6, c = i & 63; wT[c * 48 + 16 + o] = w_g[i]; }
    __syncthreads();

    const int p = blockIdx.x * 256 + t;
    const float* xb = x + (size_t)b * CC * NN;

    float xr[64];
    #pragma unroll
    for (int c = 0; c < 64; ++c) xr[c] = xb[c * NN + p];

    float4 acc[12];
    #pragma unroll
    for (int k = 0; k < 12; ++k) acc[k] = make_float4(0.f, 0.f, 0.f, 0.f);

    #pragma unroll
    for (int c = 0; c < 64; ++c) {
        const float xv = xr[c];
        const float4* w4 = (const float4*)&wT[c * 48];
        #pragma unroll
        for (int k = 0; k < 12; ++k) {
            float4 w = w4[k];
            acc[k].x += w.x * xv; acc[k].y += w.y * xv;
            acc[k].z += w.z * xv; acc[k].w += w.w * xv;
        }
    }

    // theta bf16 out: 16 B/thread, coalesced
    {
        union { u16 s[8]; uint4 v; } tb;
        tb.s[0] = f2bf(acc[0].x); tb.s[1] = f2bf(acc[0].y);
        tb.s[2] = f2bf(acc[0].z); tb.s[3] = f2bf(acc[0].w);
        tb.s[4] = f2bf(acc[1].x); tb.s[5] = f2bf(acc[1].y);
        tb.s[6] = f2bf(acc[1].z); tb.s[7] = f2bf(acc[1].w);
        *(uint4*)(theta_b + ((size_t)b * NN + p) * 8) = tb.v;
    }

    // horizontal pool via shfl_xor(1)
    const int col = t & 63, rp = t >> 6;
    float hm[40];
    #pragma unroll
    for (int k = 0; k < 10; ++k) {
        float4 a = acc[2 + k];
        hm[4 * k + 0] = a.x; hm[4 * k + 1] = a.y; hm[4 * k + 2] = a.z; hm[4 * k + 3] = a.w;
    }
    #pragma unroll
    for (int k = 0; k < 40; ++k) {
        float o = __shfl_xor(hm[k], 1, 64);
        hm[k] = fmaxf(hm[k], o);
    }
    if ((col & 1) == 0) {
        const int pc = col >> 1;
        #pragma unroll
        for (int k = 0; k < 40; ++k) pool[k * 128 + rp * 32 + pc] = hm[k];
    }
    __syncthreads();

    // vertical pool -> bf16 phi (row-major d=8) / gT (k-major)
    const int mrow0 = blockIdx.x * 2;
    for (int i = t; i < 2560; i += 256) {
        const int k = i >> 6, rem = i & 63, pr = rem >> 5, pcol = rem & 31;
        const float v = fmaxf(pool[k * 128 + (2 * pr) * 32 + pcol],
                              pool[k * 128 + (2 * pr + 1) * 32 + pcol]);
        const int m = (mrow0 + pr) * 32 + pcol;
        if (k < 8) phi_b[((size_t)b * MM + m) * 8 + k] = f2bf(v);
        else       gT_b[(size_t)b * 32 * MM + (size_t)(k - 8) * MM + m] = f2bf(v);
    }
}

// ---------------------------------------------------------------------------
// Kernel 2: MFMA flash attention (no max-subtraction; l via ones-column MFMA).
// grid (64,16), 256 threads = 4 waves; wave w owns queries qbase+16w..+15.
// Keys in 16 chunks of 64. All frags 16x16x32 bf16.
// ---------------------------------------------------------------------------
__global__ __launch_bounds__(256) void attn_kernel(
    const u16* __restrict__ theta_b, const u16* __restrict__ phi_b,
    const u16* __restrict__ gT_b, float* __restrict__ o_ws)
{
    __shared__ u16 phis[64 * 8];     // [key][8d], rows 16 B
    __shared__ u16 gts[32 * 72];     // [d][64k + pad8], rows 144 B
    __shared__ u16 Ps[64 * 72];      // [q][64k + pad8], per-wave private row blocks

    const int t = threadIdx.x;
    const int w = t >> 6, lane = t & 63;
    const int b = blockIdx.y, qbase = blockIdx.x * 64;
    const int m16 = lane & 15, quad = lane >> 4;

    // persistent A-frag: theta rows (quad 0 holds k=0..7, rest zero)
    bf16x8 thA = {0, 0, 0, 0, 0, 0, 0, 0};
    if (quad == 0)
        thA = ld_bf16x8(theta_b + ((size_t)b * NN + qbase + w * 16 + m16) * 8);

    bf16x8 onesB;
    #pragma unroll
    for (int i = 0; i < 8; ++i) onesB[i] = (short)0x3F80;   // bf16 1.0

    const f32x4 zero4 = {0.f, 0.f, 0.f, 0.f};
    f32x4 oacc0 = zero4, oacc1 = zero4, lacc = zero4;

    const u16* phg = phi_b + (size_t)b * MM * 8;
    const u16* gtg = gT_b + (size_t)b * 32 * MM;

    for (int c = 0; c < 16; ++c) {
        __syncthreads();
        if (t < 64)
            *(uint4*)(phis + t * 8) = *(const uint4*)(phg + (size_t)(c * 64 + t) * 8);
        {
            const int d = t >> 3, part = t & 7;
            *(uint4*)(gts + d * 72 + part * 8) =
                *(const uint4*)(gtg + (size_t)d * MM + c * 64 + part * 8);
        }
        __syncthreads();

        // ---- QK: 4 MFMAs (16 q x 64 k, K=32 with d=8 real) ----
        f32x4 S[4];
        #pragma unroll
        for (int kc = 0; kc < 4; ++kc) {
            bf16x8 phB = {0, 0, 0, 0, 0, 0, 0, 0};
            if (quad == 0)
                phB = ld_bf16x8(phis + (kc * 16 + m16) * 8);
            S[kc] = __builtin_amdgcn_mfma_f32_16x16x32_bf16(thA, phB, zero4, 0, 0, 0);
        }

        // ---- exp -> P (bf16, C-layout scatter to row-major LDS) ----
        #pragma unroll
        for (int kc = 0; kc < 4; ++kc) {
            #pragma unroll
            for (int r = 0; r < 4; ++r) {
                const float e = __expf(S[kc][r]);
                Ps[(w * 16 + quad * 4 + r) * 72 + kc * 16 + m16] = f2bf(e);
            }
        }
        // wave reads only its own P rows -> no barrier needed (lgkmcnt suffices)

        // ---- PV + l: per k-block of 32: A = P, B = gT rows (d), ones ----
        #pragma unroll
        for (int kblk = 0; kblk < 2; ++kblk) {
            const bf16x8 pA = ld_bf16x8(Ps + (w * 16 + m16) * 72 + kblk * 32 + quad * 8);
            const bf16x8 g0 = ld_bf16x8(gts + m16 * 72 + kblk * 32 + quad * 8);
            const bf16x8 g1 = ld_bf16x8(gts + (16 + m16) * 72 + kblk * 32 + quad * 8);
            oacc0 = __builtin_amdgcn_mfma_f32_16x16x32_bf16(pA, g0, oacc0, 0, 0, 0);
            oacc1 = __builtin_amdgcn_mfma_f32_16x16x32_bf16(pA, g1, oacc1, 0, 0, 0);
            lacc  = __builtin_amdgcn_mfma_f32_16x16x32_bf16(pA, onesB, lacc, 0, 0, 0);
        }
    }

    // ---- epilogue: o = O / l  (lacc rows align with oacc rows; all cols equal) ----
    float* dst = o_ws + ((size_t)b * NN + qbase + w * 16 + quad * 4) * 32 + m16;
    #pragma unroll
    for (int r = 0; r < 4; ++r) {
        const float inv = 1.0f / lacc[r];
        dst[r * 32]      = oacc0[r] * inv;
        dst[r * 32 + 16] = oacc1[r] * inv;
    }
}

// ---------------------------------------------------------------------------
// Kernel 3: out = gamma * (w_o @ o) + x. grid (32,16), 256 threads.
// ---------------------------------------------------------------------------
__global__ __launch_bounds__(256) void out_kernel(
    const float* __restrict__ o_ws, const float* __restrict__ w_o,
    const float* __restrict__ x, const float* __restrict__ gamma_p,
    float* __restrict__ out)
{
    __shared__ float wos[64 * 32];
    const int t = threadIdx.x;
    for (int i = t; i < 2048; i += 256) wos[i] = w_o[i];
    __syncthreads();

    const int b = blockIdx.y;
    const int xid = blockIdx.x * 256 + t;
    const int half = xid >> 12;             // uniform per block
    const int n = xid & 4095;
    const float gamma = *gamma_p;

    float4 ov[8];
    const float4* op = (const float4*)(o_ws + ((size_t)b * NN + n) * 32);
    #pragma unroll
    for (int d = 0; d < 8; ++d) ov[d] = op[d];

    const float* xb = x + (size_t)b * CC * NN;
    float* ob = out + (size_t)b * CC * NN;
    for (int ci = 0; ci < 32; ++ci) {
        const int c = half * 32 + ci;
        const float4* wr = (const float4*)(wos + c * 32);
        float acc = 0.f;
        #pragma unroll
        for (int d = 0; d < 8; ++d) {
            const float4 wv = wr[d];
            acc += wv.x * ov[d].x + wv.y * ov[d].y + wv.z * ov[d].z + wv.w * ov[d].w;
        }
        ob[c * NN + n] = gamma * acc + xb[c * NN + n];
    }
}

// ---------------------------------------------------------------------------
extern "C" void kernel_launch(void* const* d_in, const int* in_sizes, int n_in,
                              void* d_out, int out_size, void* d_ws, size_t ws_size,
                              hipStream_t stream) {
    const float* x       = (const float*)d_in[0];
    const float* w_theta = (const float*)d_in[1];
    const float* w_phi   = (const float*)d_in[2];
    const float* w_g     = (const float*)d_in[3];
    const float* w_o     = (const float*)d_in[4];
    const float* gamma   = (const float*)d_in[5];

    float* ws = (float*)d_ws;
    float* o_ws = ws;                               // 2097152 floats
    u16* theta_b = (u16*)(ws + 2097152);            // 524288 u16
    u16* phi_b   = theta_b + 524288;                // 131072 u16
    u16* gT_b    = phi_b + 131072;                  // 524288 u16
    float* out   = (float*)d_out;

    prep_kernel<<<dim3(16, 16), 256, 0, stream>>>(x, w_theta, w_phi, w_g, theta_b, phi_b, gT_b);
    attn_kernel<<<dim3(64, 16), 256, 0, stream>>>(theta_b, phi_b, gT_b, o_ws);
    out_kernel<<<dim3(32, 16), 256, 0, stream>>>(o_ws, w_o, x, gamma, out);
}

// Round 4
// 120.219 us; speedup vs baseline: 3.2248x; 1.1402x over previous
//
#include <hip/hip_runtime.h>

#define BB 16
#define CC 64
#define NN 4096      // H*W
#define MM 1024      // pooled spatial

typedef unsigned short u16;
typedef unsigned int u32;
typedef __attribute__((ext_vector_type(8))) short bf16x8;
typedef __attribute__((ext_vector_type(4))) float f32x4;

__device__ inline u16 f2bf(float f) {
    union { float f; u32 u; } v; v.f = f;
    return (u16)((v.u + 0x7FFFu + ((v.u >> 16) & 1u)) >> 16);
}
__device__ inline bf16x8 ld_bf16x8(const u16* p) {
    union { uint4 u; bf16x8 b; } c; c.u = *(const uint4*)p; return c.b;
}
// build frag from two 8B runs (K-permuted g reads)
__device__ inline bf16x8 ld2_bf16x8(const u16* p0, const u16* p1) {
    union { uint2 u[2]; bf16x8 b; } c;
    c.u[0] = *(const uint2*)p0;
    c.u[1] = *(const uint2*)p1;
    return c.b;
}
__device__ inline uint2 pack4(u16 a, u16 b, u16 c, u16 d) {
    uint2 r; r.x = (u32)a | ((u32)b << 16); r.y = (u32)c | ((u32)d << 16); return r;
}

// workspace (u16):
// theta_b [B][N][8]  : 524288
// phi_b   [B][M][8]  : 131072
// gT_b    [B][32][M] : 524288

// ---------------------------------------------------------------------------
// Kernel 1: 1x1 convs + 2x2 maxpool -> bf16 theta/phi/gT.
// grid (16,16): block = 256 px (4 image rows). Wave w computes k-outputs
// 12w..12w+11 (0..7 theta, 8..15 phi, 16..47 g) for all 256 px; lane owns
// 4 horizontally-adjacent px (float4 x loads straight from global/L2).
// Pooling: horizontal in-lane, vertical via shfl_xor(16).
// ---------------------------------------------------------------------------
__global__ __launch_bounds__(256) void prep_kernel(
    const float* __restrict__ x, const float* __restrict__ w_theta,
    const float* __restrict__ w_phi, const float* __restrict__ w_g,
    u16* __restrict__ theta_b, u16* __restrict__ phi_b, u16* __restrict__ gT_b)
{
    __shared__ float wT[64 * 48];    // [c][k] transposed weights

    const int t = threadIdx.x, w = t >> 6, l = t & 63;
    const int b = blockIdx.y;

    for (int i = t; i < 64 * 8; i += 256)  { int o = i >> 6, c = i & 63; wT[c * 48 + o] = w_theta[i]; }
    for (int i = t; i < 64 * 8; i += 256)  { int o = i >> 6, c = i & 63; wT[c * 48 + 8 + o] = w_phi[i]; }
    for (int i = t; i < 64 * 32; i += 256) { int o = i >> 6, c = i & 63; wT[c * 48 + 16 + o] = w_g[i]; }
    __syncthreads();

    const int nbase = blockIdx.x * 256;
    const float* xb = x + (size_t)b * CC * NN + nbase + 4 * l;

    float acc[12][4];
    #pragma unroll
    for (int k = 0; k < 12; ++k)
        #pragma unroll
        for (int p = 0; p < 4; ++p) acc[k][p] = 0.f;

    #pragma unroll 4
    for (int c = 0; c < 64; ++c) {
        const float4 xv = *(const float4*)(xb + c * NN);
        const float4* wp = (const float4*)(wT + c * 48 + w * 12);
        const float4 wa = wp[0], wb = wp[1], wc = wp[2];
        const float wk[12] = {wa.x, wa.y, wa.z, wa.w, wb.x, wb.y, wb.z, wb.w,
                              wc.x, wc.y, wc.z, wc.w};
        #pragma unroll
        for (int k = 0; k < 12; ++k) {
            acc[k][0] += wk[k] * xv.x; acc[k][1] += wk[k] * xv.y;
            acc[k][2] += wk[k] * xv.z; acc[k][3] += wk[k] * xv.w;
        }
    }

    // ---- theta (wave 0 owns all 8 theta channels): pack 8 per px ----
    if (w == 0) {
        #pragma unroll
        for (int p = 0; p < 4; ++p) {
            union { u16 s[8]; uint4 v; } tb;
            #pragma unroll
            for (int k = 0; k < 8; ++k) tb.s[k] = f2bf(acc[k][p]);
            *(uint4*)(theta_b + ((size_t)b * NN + nbase + 4 * l + p) * 8) = tb.v;
        }
    }

    // ---- pooled outputs (kg >= 8): horizontal in-lane, vertical shfl ----
    const int start = (w == 0) ? 8 : 0;    // wave-uniform
    float v0[12], v1[12];
    #pragma unroll
    for (int k = 0; k < 12; ++k) {
        if (k < start) continue;
        float h0 = fmaxf(acc[k][0], acc[k][1]);
        float h1 = fmaxf(acc[k][2], acc[k][3]);
        v0[k] = fmaxf(h0, __shfl_xor(h0, 16, 64));
        v1[k] = fmaxf(h1, __shfl_xor(h1, 16, 64));
    }
    if ((l & 16) == 0) {
        const int prow = l >> 5;
        const int m = (blockIdx.x * 2 + prow) * 32 + 2 * (l & 15);
        #pragma unroll
        for (int k = 0; k < 12; ++k) {
            if (k < start) continue;
            const int kg = w * 12 + k;
            if (kg < 16) {
                phi_b[((size_t)b * MM + m) * 8 + (kg - 8)]     = f2bf(v0[k]);
                phi_b[((size_t)b * MM + m + 1) * 8 + (kg - 8)] = f2bf(v1[k]);
            } else {
                *(u32*)(gT_b + (size_t)b * 32 * MM + (size_t)(kg - 16) * MM + m) =
                    (u32)f2bf(v0[k]) | ((u32)f2bf(v1[k]) << 16);
            }
        }
    }
}

// ---------------------------------------------------------------------------
// Kernel 2: fused attention + output conv + residual.
// grid (64,16), 256 threads = 4 waves; wave w owns queries qbase+16w..+15.
// S^T = mfma(phi, theta) -> C-frag holds, per lane, 4 keys of ONE query ->
// exp+bf16 pack is the PV B-frag directly (K-axis permuted; g read from LDS
// with the same permutation). O^T accumulated via mfma(g, P); denominator
// via mfma(ones, P) lands in the same columns -> in-lane normalize.
// Epilogue: O^T -> 5KB LDS transpose -> B-frag; out = gamma*(w_o@o)+x via
// 4 MFMAs with w_o A-frags held in registers.
// ---------------------------------------------------------------------------
__global__ __launch_bounds__(256, 4) void attn_out_kernel(
    const u16* __restrict__ theta_b, const u16* __restrict__ phi_b,
    const u16* __restrict__ gT_b, const float* __restrict__ w_o,
    const float* __restrict__ x, const float* __restrict__ gamma_p,
    float* __restrict__ out)
{
    __shared__ u16 gs[32 * 136];   // [d][key 0..127 + pad], 16B-aligned rows
    __shared__ u16 oS[64 * 40];    // [q_local][d 0..31 + pad]

    const int t = threadIdx.x, w = t >> 6, lane = t & 63;
    const int m16 = lane & 15, quad = lane >> 4;
    const int b = blockIdx.y, qbase = blockIdx.x * 64;

    // persistent theta B-frag: B[n=q][k=d], quad0 real
    bf16x8 thB = {0, 0, 0, 0, 0, 0, 0, 0};
    if (quad == 0)
        thB = ld_bf16x8(theta_b + ((size_t)b * NN + qbase + w * 16 + m16) * 8);

    // persistent w_o A-frags: A[m=c][k=d], c = cf*16+m16, d = quad*8+j
    bf16x8 woA[4];
    #pragma unroll
    for (int cf = 0; cf < 4; ++cf) {
        const float* wp = w_o + (cf * 16 + m16) * 32 + quad * 8;
        const float4 f0 = *(const float4*)wp;
        const float4 f1 = *(const float4*)(wp + 4);
        bf16x8 a;
        a[0] = f2bf(f0.x); a[1] = f2bf(f0.y); a[2] = f2bf(f0.z); a[3] = f2bf(f0.w);
        a[4] = f2bf(f1.x); a[5] = f2bf(f1.y); a[6] = f2bf(f1.z); a[7] = f2bf(f1.w);
        woA[cf] = a;
    }

    bf16x8 onesA;
    #pragma unroll
    for (int i = 0; i < 8; ++i) onesA[i] = (short)0x3F80;

    const f32x4 zero4 = {0.f, 0.f, 0.f, 0.f};
    f32x4 oT0 = zero4, oT1 = zero4, lacc = zero4;

    const u16* phg = phi_b + (size_t)b * MM * 8;
    const u16* gtg = gT_b + (size_t)b * 32 * MM;

    for (int it = 0; it < 8; ++it) {
        const int keybase = it * 128;
        __syncthreads();
        #pragma unroll
        for (int p2 = 0; p2 < 2; ++p2) {
            const int d = p2 * 16 + (t >> 4);
            const int k0 = (t & 15) * 8;
            *(uint4*)(gs + d * 136 + k0) =
                *(const uint4*)(gtg + (size_t)d * MM + keybase + k0);
        }
        __syncthreads();

        #pragma unroll
        for (int kblk = 0; kblk < 4; ++kblk) {
            // S^T: A = phi (m=key), B = theta (n=q)
            bf16x8 phA0 = {0, 0, 0, 0, 0, 0, 0, 0};
            bf16x8 phA1 = {0, 0, 0, 0, 0, 0, 0, 0};
            if (quad == 0) {
                phA0 = ld_bf16x8(phg + (size_t)(keybase + kblk * 32 + m16) * 8);
                phA1 = ld_bf16x8(phg + (size_t)(keybase + kblk * 32 + 16 + m16) * 8);
            }
            const f32x4 Sa = __builtin_amdgcn_mfma_f32_16x16x32_bf16(phA0, thB, zero4, 0, 0, 0);
            const f32x4 Sb = __builtin_amdgcn_mfma_f32_16x16x32_bf16(phA1, thB, zero4, 0, 0, 0);

            // P B-frag, entirely in registers: slot j<4 -> key 32kblk+4*quad+j,
            // slot j>=4 -> key 32kblk+16+4*quad+(j-4)
            bf16x8 pB;
            #pragma unroll
            for (int r = 0; r < 4; ++r) {
                pB[r]     = (short)f2bf(__expf(Sa[r]));
                pB[4 + r] = (short)f2bf(__expf(Sb[r]));
            }

            // g A-frags with the SAME key permutation
            const u16* g0p = gs + m16 * 136 + kblk * 32 + quad * 4;
            const u16* g1p = gs + (16 + m16) * 136 + kblk * 32 + quad * 4;
            const bf16x8 gA0 = ld2_bf16x8(g0p, g0p + 16);
            const bf16x8 gA1 = ld2_bf16x8(g1p, g1p + 16);

            oT0  = __builtin_amdgcn_mfma_f32_16x16x32_bf16(gA0, pB, oT0, 0, 0, 0);
            oT1  = __builtin_amdgcn_mfma_f32_16x16x32_bf16(gA1, pB, oT1, 0, 0, 0);
            lacc = __builtin_amdgcn_mfma_f32_16x16x32_bf16(onesA, pB, lacc, 0, 0, 0);
        }
    }

    // ---- normalize in-lane, transpose via 5KB LDS ----
    const float inv = 1.0f / lacc[0];   // all rows of lacc equal l[q=m16]
    u16* orow = oS + (w * 16 + m16) * 40;
    *(uint2*)(orow + quad * 4) =
        pack4(f2bf(oT0[0] * inv), f2bf(oT0[1] * inv), f2bf(oT0[2] * inv), f2bf(oT0[3] * inv));
    *(uint2*)(orow + 16 + quad * 4) =
        pack4(f2bf(oT1[0] * inv), f2bf(oT1[1] * inv), f2bf(oT1[2] * inv), f2bf(oT1[3] * inv));
    __syncthreads();

    // ---- output conv: D[m=c][n=px] = w_o @ o ----
    const bf16x8 oB = ld_bf16x8(oS + (w * 16 + m16) * 40 + quad * 8);
    const float gamma = *gamma_p;
    #pragma unroll
    for (int cf = 0; cf < 4; ++cf) {
        const f32x4 D = __builtin_amdgcn_mfma_f32_16x16x32_bf16(woA[cf], oB, zero4, 0, 0, 0);
        #pragma unroll
        for (int r = 0; r < 4; ++r) {
            const int c = cf * 16 + quad * 4 + r;
            const size_t adr = ((size_t)b * CC + c) * NN + qbase + w * 16 + m16;
            out[adr] = gamma * D[r] + x[adr];
        }
    }
}

// ---------------------------------------------------------------------------
extern "C" void kernel_launch(void* const* d_in, const int* in_sizes, int n_in,
                              void* d_out, int out_size, void* d_ws, size_t ws_size,
                              hipStream_t stream) {
    const float* x       = (const float*)d_in[0];
    const float* w_theta = (const float*)d_in[1];
    const float* w_phi   = (const float*)d_in[2];
    const float* w_g     = (const float*)d_in[3];
    const float* w_o     = (const float*)d_in[4];
    const float* gamma   = (const float*)d_in[5];

    u16* theta_b = (u16*)d_ws;                      // 524288
    u16* phi_b   = theta_b + 524288;                // 131072
    u16* gT_b    = phi_b + 131072;                  // 524288
    float* out   = (float*)d_out;

    prep_kernel<<<dim3(16, 16), 256, 0, stream>>>(x, w_theta, w_phi, w_g,
                                                  theta_b, phi_b, gT_b);
    attn_out_kernel<<<dim3(64, 16), 256, 0, stream>>>(theta_b, phi_b, gT_b,
                                                      w_o, x, gamma, out);
}